// Round 1
// baseline (592.112 us; speedup 1.0000x reference)
//
#include <hip/hip_runtime.h>

// PrRoI pooling (FeaturePool): N=128 boxes, C=256, H=W=64 fp32 feature map,
// POOLED 5x5, K_CELLS=6 (7 samples/axis/bin). Separable form:
//   out[n,c,i,j] = inv_win * sum_p sum_q ch[i,p]*cw[j,q]*feat[n,c,hidx[i,p],widx[j,q]]
// Coefficients depend only on bb[n,0:2] (reference uses x2=2*x1, y2=y1+x1).
// Block = (one n, 8 channels); Phase A does the h-axis pool with coalesced
// 32-wide row segments into LDS, Phase B the w-axis pool from LDS.

constexpr int PH = 5, PW = 5;
constexpr int KS = 7;        // K_CELLS + 1 samples per bin
constexpr int SPAN = 32;     // max w-index span is <=23; 32 gives margin
constexpr int SPANP = 33;    // +1 pad: conflict-free LDS
constexpr int CPB = 8;       // channels per block
constexpr int NC = 256, FH = 64, FW = 64;

__global__ __launch_bounds__(256) void prroi_kernel(
    const float* __restrict__ feat,
    const float* __restrict__ bb,
    float* __restrict__ out)
{
    __shared__ float s_ch[PH * KS];
    __shared__ int   s_hoff[PH * KS];   // hidx * FW (pre-scaled row offset)
    __shared__ float s_cw[PW * KS];
    __shared__ int   s_wloc[PW * KS];   // widx - w0, clamped to [0, SPAN-1]
    __shared__ float s_rows[CPB][PH][SPANP];
    __shared__ float s_inv;
    __shared__ int   s_w0;

    const int n   = blockIdx.x;
    const int c0  = blockIdx.y * CPB;
    const int tid = threadIdx.x;

    // ---- per-box geometry (all threads; scalar-ish, broadcast loads) ----
    const float scale = 0.0625f;
    const float x1 = bb[n * 4 + 0];
    const float y1 = bb[n * 4 + 1];
    const float rx1 = x1 * scale,        ry1 = y1 * scale;
    const float rx2 = (x1 + x1) * scale, ry2 = (y1 + x1) * scale;
    const float bin_w = (rx2 - rx1) / 5.0f;
    const float bin_h = (ry2 - ry1) / 5.0f;

    if (tid == 0) {
        s_w0  = (int)floorf(rx1);
        s_inv = 1.0f / fmaxf(bin_w * bin_h, 1e-30f);  // win>0 always (x1>=32)
    }

    // ---- coefficient tables: 70 entries (5 bins x 7 samples x 2 axes) ----
    if (tid < 2 * PH * KS) {
        const bool is_h = tid < PH * KS;
        const int  e    = is_h ? tid : tid - PH * KS;
        const int  i    = e / KS;           // bin index
        const int  p    = e % KS;           // sample index 0..6
        const float r1   = is_h ? ry1 : rx1;
        const float bsz  = is_h ? bin_h : bin_w;
        const int   size = is_h ? FH : FW;
        const float start = r1 + (float)i * bsz;
        const float end   = start + bsz;
        const float base  = floorf(start);
        const float ce    = ceilf(end);
        // coef[p] = X0(p)*[p<6] + X1(p-1)*[p>=1], each masked by (base+k < ce)
        float coef = 0.0f;
        if (p < KS - 1) {
            const float w_it = base + (float)p;
            if (w_it < ce) {
                const float alpha = fmaxf(start, w_it) - w_it;
                const float lim   = fminf(end, w_it + 1.0f) - w_it;
                coef += lim - 0.5f * lim * lim - alpha + 0.5f * alpha * alpha;
            }
        }
        if (p > 0) {
            const float w_it = base + (float)(p - 1);
            if (w_it < ce) {
                const float alpha = fmaxf(start, w_it) - w_it;
                const float lim   = fminf(end, w_it + 1.0f) - w_it;
                coef += 0.5f * lim * lim - 0.5f * alpha * alpha;
            }
        }
        int idx = (int)base + p;
        if (idx < 0 || idx >= size) coef = 0.0f;  // reference valid-mask
        idx = min(max(idx, 0), size - 1);         // reference clip
        if (is_h) {
            s_ch[e]   = coef;
            s_hoff[e] = idx * FW;
        } else {
            s_cw[e]   = coef;
            int wl = idx - (int)floorf(rx1);
            s_wloc[e] = min(max(wl, 0), SPAN - 1);
        }
    }
    __syncthreads();

    // ---- Phase A: h-axis pool, coalesced 32-wide row segments ----
    const int wl = tid & (SPAN - 1);
    const int cl = tid >> 5;            // 0..7
    int w = s_w0 + wl;
    if (w > FW - 1) w = FW - 1;         // defensive; analytically dead
    const float* fp = feat + ((size_t)(n * NC + c0 + cl) * (FH * FW)) + w;

    float acc[PH];
    #pragma unroll
    for (int i = 0; i < PH; ++i) acc[i] = 0.0f;
    #pragma unroll
    for (int i = 0; i < PH; ++i) {
        #pragma unroll
        for (int p = 0; p < KS; ++p) {
            acc[i] += s_ch[i * KS + p] * fp[s_hoff[i * KS + p]];
        }
    }
    #pragma unroll
    for (int i = 0; i < PH; ++i) s_rows[cl][i][wl] = acc[i];
    __syncthreads();

    // ---- Phase B: w-axis pool, one output per thread ----
    if (tid < CPB * PH * PW) {
        const int cl2 = tid / (PH * PW);
        const int bin = tid % (PH * PW);
        const int i   = bin / PW;
        const int j   = bin % PW;
        float o = 0.0f;
        #pragma unroll
        for (int q = 0; q < KS; ++q) {
            o += s_cw[j * KS + q] * s_rows[cl2][i][s_wloc[j * KS + q]];
        }
        out[(size_t)(n * NC + c0 + cl2) * (PH * PW) + bin] = o * s_inv;
    }
}

extern "C" void kernel_launch(void* const* d_in, const int* in_sizes, int n_in,
                              void* d_out, int out_size, void* d_ws, size_t ws_size,
                              hipStream_t stream) {
    const float* feat = (const float*)d_in[0];
    const float* bb   = (const float*)d_in[1];
    float* out        = (float*)d_out;
    const int N = in_sizes[1] / 4;          // 128
    dim3 grid(N, NC / CPB);                 // 128 x 32 blocks
    prroi_kernel<<<grid, 256, 0, stream>>>(feat, bb, out);
}

// Round 2
// 585.713 us; speedup vs baseline: 1.0109x; 1.0109x over previous
//
#include <hip/hip_runtime.h>

// PrRoI pooling (FeaturePool): N=128 boxes, C=256, H=W=64 fp32, pooled 5x5.
// Separable: out[n,c,i,j] = inv_win * sum_r sum_w rowc[i][r]*colc[j][w]*feat[n,c,r,w]
// R1 change: Phase A now iterates UNIQUE rows (span <= 22, avg ~12) with a
// per-row x per-bin coefficient table, instead of 5x7=35 (bin,sample) loads.
// Coefficient table laid out r-major, padded to 8 -> one b128+b32 LDS read/row.

constexpr int PH = 5, PW = 5;
constexpr int KS = 7;          // K_CELLS + 1 samples per bin (Phase B)
constexpr int SPAN = 32;       // w-lane coverage (max col span <= 22)
constexpr int SPANP = 33;      // +1 pad for conflict-free LDS writes
constexpr int CPB = 8;         // channels per block
constexpr int ROWMAX = 24;     // max unique row span (<=22) padded
constexpr int NC = 256, FH = 64, FW = 64;

__global__ __launch_bounds__(256) void prroi_kernel(
    const float* __restrict__ feat,
    const float* __restrict__ bb,
    float* __restrict__ out)
{
    __shared__ float s_rowc[ROWMAX][8];   // [row-offset][bin], cols 5..7 unused
    __shared__ float s_cw[PW * KS];
    __shared__ int   s_wloc[PW * KS];     // widx - w0, clamped to [0, SPAN-1]
    __shared__ float s_rows[CPB][PH][SPANP];
    __shared__ float s_inv;
    __shared__ int   s_w0, s_h0, s_nrows;

    const int n   = blockIdx.x;
    const int c0  = blockIdx.y * CPB;
    const int tid = threadIdx.x;

    // ---- per-box geometry (broadcast loads) ----
    const float scale = 0.0625f;
    const float x1 = bb[n * 4 + 0];
    const float y1 = bb[n * 4 + 1];
    const float rx1 = x1 * scale,        ry1 = y1 * scale;
    const float rx2 = (x1 + x1) * scale, ry2 = (y1 + x1) * scale;
    const float bin_w = (rx2 - rx1) / 5.0f;
    const float bin_h = (ry2 - ry1) / 5.0f;
    const int h0 = (int)floorf(ry1);
    const int w0 = (int)floorf(rx1);

    if (tid == 192) {
        s_w0  = w0;
        s_h0  = h0;
        int nr = (int)ceilf(ry2) - h0 + 1;      // rows h0 .. ceil(ry2)
        s_nrows = min(max(nr, 1), ROWMAX);
        s_inv = 1.0f / fmaxf(bin_w * bin_h, 1e-30f);
    }

    // ---- per-row x per-bin H coefficients: 120 threads ----
    if (tid < PH * ROWMAX) {
        const int i = tid / ROWMAX;     // bin
        const int r = tid % ROWMAX;     // row offset from h0
        const int h = h0 + r;
        const float start = ry1 + (float)i * bin_h;
        const float end   = start + bin_h;
        const float base  = floorf(start);
        const float ce    = ceilf(end);
        const int   p     = h - (int)base;   // sample index within bin
        float coef = 0.0f;
        if (p >= 0 && p <= KS - 1) {
            if (p <= KS - 2) {               // X0 piece at w_iter = h
                const float w_it = (float)h;
                if (w_it < ce) {
                    const float alpha = fmaxf(start, w_it) - w_it;
                    const float lim   = fminf(end, w_it + 1.0f) - w_it;
                    coef += lim - 0.5f * lim * lim - alpha + 0.5f * alpha * alpha;
                }
            }
            if (p >= 1) {                    // X1 piece at w_iter = h-1
                const float w_it = (float)(h - 1);
                if (w_it < ce) {
                    const float alpha = fmaxf(start, w_it) - w_it;
                    const float lim   = fminf(end, w_it + 1.0f) - w_it;
                    coef += 0.5f * lim * lim - 0.5f * alpha * alpha;
                }
            }
        }
        if (h < 0 || h >= FH) coef = 0.0f;   // reference valid-mask
        s_rowc[r][i] = coef;
        if (i == 0) { s_rowc[r][5] = 0.f; s_rowc[r][6] = 0.f; s_rowc[r][7] = 0.f; }
    }

    // ---- W sample table (Phase B form): 35 threads ----
    if (tid >= 128 && tid < 128 + PW * KS) {
        const int e = tid - 128;
        const int j = e / KS;
        const int q = e % KS;
        const float start = rx1 + (float)j * bin_w;
        const float end   = start + bin_w;
        const float base  = floorf(start);
        const float ce    = ceilf(end);
        float coef = 0.0f;
        if (q <= KS - 2) {
            const float w_it = base + (float)q;
            if (w_it < ce) {
                const float alpha = fmaxf(start, w_it) - w_it;
                const float lim   = fminf(end, w_it + 1.0f) - w_it;
                coef += lim - 0.5f * lim * lim - alpha + 0.5f * alpha * alpha;
            }
        }
        if (q >= 1) {
            const float w_it = base + (float)(q - 1);
            if (w_it < ce) {
                const float alpha = fmaxf(start, w_it) - w_it;
                const float lim   = fminf(end, w_it + 1.0f) - w_it;
                coef += 0.5f * lim * lim - 0.5f * alpha * alpha;
            }
        }
        int idx = (int)base + q;
        if (idx < 0 || idx >= FW) coef = 0.0f;  // reference valid-mask
        idx = min(max(idx, 0), FW - 1);         // reference clip
        s_cw[e]   = coef;
        s_wloc[e] = min(max(idx - w0, 0), SPAN - 1);
    }
    __syncthreads();

    // ---- Phase A: iterate unique rows, coalesced 32-wide segments ----
    const int wl = tid & (SPAN - 1);
    const int cl = tid >> 5;            // 0..7
    int w = s_w0 + wl;
    if (w > FW - 1) w = FW - 1;         // defensive; analytically dead
    const float* fp = feat + ((size_t)(n * NC + c0 + cl) * (FH * FW))
                    + (size_t)s_h0 * FW + w;
    const int nrows = s_nrows;

    float acc[PH] = {0.f, 0.f, 0.f, 0.f, 0.f};
    for (int r = 0; r < nrows; ++r) {
        const float v  = fp[r * FW];
        const float4 c0123 = *(const float4*)&s_rowc[r][0];
        const float  c4    = s_rowc[r][4];
        acc[0] += c0123.x * v;
        acc[1] += c0123.y * v;
        acc[2] += c0123.z * v;
        acc[3] += c0123.w * v;
        acc[4] += c4 * v;
    }
    #pragma unroll
    for (int i = 0; i < PH; ++i) s_rows[cl][i][wl] = acc[i];
    __syncthreads();

    // ---- Phase B: w-axis pool, one output per thread ----
    if (tid < CPB * PH * PW) {
        const int cl2 = tid / (PH * PW);
        const int bin = tid % (PH * PW);
        const int i   = bin / PW;
        const int j   = bin % PW;
        float o = 0.0f;
        #pragma unroll
        for (int q = 0; q < KS; ++q) {
            o += s_cw[j * KS + q] * s_rows[cl2][i][s_wloc[j * KS + q]];
        }
        out[(size_t)(n * NC + c0 + cl2) * (PH * PW) + bin] = o * s_inv;
    }
}

extern "C" void kernel_launch(void* const* d_in, const int* in_sizes, int n_in,
                              void* d_out, int out_size, void* d_ws, size_t ws_size,
                              hipStream_t stream) {
    const float* feat = (const float*)d_in[0];
    const float* bb   = (const float*)d_in[1];
    float* out        = (float*)d_out;
    const int N = in_sizes[1] / 4;          // 128
    dim3 grid(N, NC / CPB);                 // 128 x 32 blocks
    prroi_kernel<<<grid, 256, 0, stream>>>(feat, bb, out);
}